// Round 14
// baseline (232.970 us; speedup 1.0000x reference)
//
#include <hip/hip_runtime.h>

#define N_CH 128   // IN_CH == OUT_CH == 128

typedef _Float16 half8  __attribute__((ext_vector_type(8)));
typedef _Float16 half4v __attribute__((ext_vector_type(4)));
typedef float    floatx4 __attribute__((ext_vector_type(4)));

// ---------------- prep: zero cnt/cnt_lo + W/W1 fp16 conversions ----------------

__global__ void k_prep(int* __restrict__ cnt, int* __restrict__ cntlo,
                       const float* __restrict__ W,  _Float16* __restrict__ wh,
                       const float* __restrict__ W1, _Float16* __restrict__ w1h,
                       int n) {
    int i = blockIdx.x * blockDim.x + threadIdx.x;
    if (i < n) { cnt[i] = 0; cntlo[i] = 0; }
    int nw4  = N_CH * N_CH / 4;
    int nw14 = 64 * N_CH / 4;
    if (i < nw4) {
        float4 v = ((const float4*)W)[i];
        half4v o;
        o[0] = (_Float16)v.x; o[1] = (_Float16)v.y; o[2] = (_Float16)v.z; o[3] = (_Float16)v.w;
        ((half4v*)wh)[i] = o;
    } else if (i < nw4 + nw14) {
        int j = i - nw4;
        float4 v = ((const float4*)W1)[j];
        half4v o;
        o[0] = (_Float16)v.x; o[1] = (_Float16)v.y; o[2] = (_Float16)v.z; o[3] = (_Float16)v.w;
        ((half4v*)w1h)[j] = o;
    }
}

// ---------------- CSR build (bucketed by source range) ----------------

__global__ void k_count(const int* __restrict__ src, const int* __restrict__ dst,
                        int* __restrict__ cnt, int* __restrict__ cntlo,
                        int E, int nhalf) {
    int e = blockIdx.x * blockDim.x + threadIdx.x;
    if (e < E) {
        int d = dst[e];
        atomicAdd(&cnt[d], 1);
        if (src[e] < nhalf) atomicAdd(&cntlo[d], 1);
    }
}

// scan pass 1: per-block (1024) local exclusive scan of PADDED counts + block total
__global__ __launch_bounds__(1024) void k_scan1(const int* __restrict__ cnt,
                                                int* __restrict__ offs,
                                                int* __restrict__ bsum, int n) {
    __shared__ int ssum[16];
    int tid = threadIdx.x;
    int lane = tid & 63, wid = tid >> 6;
    int i = blockIdx.x * 1024 + tid;
    int v = (i < n) ? ((cnt[i] + 7) & ~7) : 0;   // pad to multiple of 8
    int x = v;
    #pragma unroll
    for (int off = 1; off < 64; off <<= 1) {
        int y = __shfl_up(x, off, 64);
        if (lane >= off) x += y;
    }
    if (lane == 63) ssum[wid] = x;
    __syncthreads();
    if (wid == 0 && lane < 16) {
        int s = ssum[lane];
        #pragma unroll
        for (int off = 1; off < 16; off <<= 1) {
            int y = __shfl_up(s, off, 64);
            if (lane >= off) s += y;
        }
        ssum[lane] = s;
    }
    __syncthreads();
    int waveoff = (wid > 0) ? ssum[wid - 1] : 0;
    int incl = x + waveoff;
    if (i < n) offs[i] = incl - v;          // local exclusive (padded)
    if (tid == 1023) bsum[blockIdx.x] = incl;
}

// scan pass 2 (fused block-sum prefix) + finalize: add base, cur_lo/cur_hi,
// dinv, CSR tail pads. Node i's region: [o, o+cnt_lo) lo-bucket,
// [o+cnt_lo, o+c) hi-bucket, [c, cp) zero-row pads.
__global__ __launch_bounds__(256) void k_scan3(const int* __restrict__ cnt,
                                               const int* __restrict__ cntlo,
                                               int* __restrict__ offs,
                                               const int* __restrict__ bsum,
                                               int* __restrict__ curlo,
                                               int* __restrict__ curhi,
                                               float* __restrict__ dinv,
                                               unsigned short* __restrict__ csr,
                                               int n, int nb) {
    __shared__ int sbb[64];
    int tid = threadIdx.x;
    if (tid < 64) {
        int v = (tid < nb) ? bsum[tid] : 0;
        int x = v;
        #pragma unroll
        for (int off = 1; off < 64; off <<= 1) {
            int y = __shfl_up(x, off, 64);
            if (tid >= off) x += y;
        }
        sbb[tid] = x - v;   // exclusive base per 1024-chunk
    }
    __syncthreads();
    int i = blockIdx.x * blockDim.x + tid;
    if (i < n) {
        int o = offs[i] + sbb[i >> 10];
        offs[i]  = o;
        curlo[i] = o;
        curhi[i] = o + cntlo[i];
        int c = cnt[i];
        dinv[i] = rsqrtf((float)(c + 1));   // deg includes self-loop
        int cp = (c + 7) & ~7;
        unsigned short zn = (unsigned short)n;
        for (int j = c; j < cp; ++j) csr[o + j] = zn;   // pad -> zero row
    }
}

// fill: ushort src index, bucketed (lo sources first within each node region)
__global__ void k_fill(const int* __restrict__ src, const int* __restrict__ dst,
                       int* __restrict__ curlo, int* __restrict__ curhi,
                       unsigned short* __restrict__ csr, int E, int nhalf) {
    int e = blockIdx.x * blockDim.x + threadIdx.x;
    if (e < E) {
        int d = dst[e];
        int s = src[e];
        int p = (s < nhalf) ? atomicAdd(&curlo[d], 1) : atomicAdd(&curhi[d], 1);
        csr[p] = (unsigned short)s;
    }
}

// ---------------- u0 = fp16(dinv * x); zero row n of both buffers ----------------

__global__ void k_scale(const float* __restrict__ x, const float* __restrict__ dinv,
                        _Float16* __restrict__ u0, _Float16* __restrict__ u1, int n) {
    int i = blockIdx.x * blockDim.x + threadIdx.x;
    int nx4 = n * (N_CH / 4);
    if (i < nx4) {
        float d = dinv[i >> 5];
        float4 v = ((const float4*)x)[i];
        half4v o;
        o[0] = (_Float16)(d * v.x); o[1] = (_Float16)(d * v.y);
        o[2] = (_Float16)(d * v.z); o[3] = (_Float16)(d * v.w);
        ((half4v*)u0)[i] = o;
    } else if (i < nx4 + 64) {   // zero row n of u0 (32 granules) and u1 (32)
        int j = i - nx4;
        half4v zz; zz[0] = (_Float16)0.f; zz[1] = (_Float16)0.f; zz[2] = (_Float16)0.f; zz[3] = (_Float16)0.f;
        _Float16* dst16 = (j < 32) ? u0 : u1;
        ((half4v*)(dst16 + (size_t)n * N_CH))[j & 31] = zz;
    }
}

// ---------------- one hop, half-row split (unchanged from round 13) ----------------
// out[i] = scale_i * ( u[i] + sum_s u[s] ).
// Two passes per dispatch (pass = blockIdx >= nblk); pass p covers bytes
// [p*128, p*128+128) of every row. With the bucket-ordered CSR, waves gather
// lo-source rows first then hi-source rows -> instantaneous hot set ~3.2 MB.
// 8-lane group per node (8 nodes/wave, 32/block); group-uniform uint4 index
// load; 8 rows (64 lines/wave) in flight; no cross-lane reduce.

__global__ __launch_bounds__(256) void k_hop8(const _Float16* __restrict__ hin,
                                              _Float16* __restrict__ hout,
                                              const int* __restrict__ offs,
                                              const int* __restrict__ cnt,
                                              const float* __restrict__ dinv,
                                              const unsigned short* __restrict__ csr,
                                              int n, int squared, int nblk) {
    int pass = (blockIdx.x >= nblk) ? 1 : 0;
    int bid  = blockIdx.x - pass * nblk;
    int tid  = threadIdx.x;
    int node = bid * 32 + (tid >> 3);
    int c8   = tid & 7;
    if (node >= n) return;
    int cbase = pass * 8 + c8;
    float di = dinv[node];
    float sc = squared ? di * di : di;
    int s0 = offs[node];
    int cp = (cnt[node] + 7) & ~7;          // padded count
    const uint4* qlst = (const uint4*)(csr + s0);   // 16B-aligned (offsets mult of 8)
    half8 self = ((const half8*)(hin + (size_t)node * N_CH))[cbase];
    float acc[8];
    #pragma unroll
    for (int j = 0; j < 8; ++j) acc[j] = (float)self[j];
    int nq = cp >> 3;
    for (int q = 0; q < nq; ++q) {
        uint4 pk = qlst[q];                 // group-uniform 8-index load
        int idx[8];
        idx[0] = pk.x & 0xFFFF; idx[1] = pk.x >> 16;
        idx[2] = pk.y & 0xFFFF; idx[3] = pk.y >> 16;
        idx[4] = pk.z & 0xFFFF; idx[5] = pk.z >> 16;
        idx[6] = pk.w & 0xFFFF; idx[7] = pk.w >> 16;
        half8 u[8];
        #pragma unroll
        for (int i = 0; i < 8; ++i)
            u[i] = ((const half8*)(hin + (size_t)idx[i] * N_CH))[cbase];
        #pragma unroll
        for (int i = 0; i < 8; ++i)
            #pragma unroll
            for (int j = 0; j < 8; ++j) acc[j] += (float)u[i][j];
    }
    half8 o;
    #pragma unroll
    for (int j = 0; j < 8; ++j) o[j] = (_Float16)(sc * acc[j]);
    ((half8*)(hout + (size_t)node * N_CH))[cbase] = o;
}

// ---------------- z = h @ W^T + b : fp16 MFMA GEMM ----------------

__global__ __launch_bounds__(256) void k_zlin_mfma(const _Float16* __restrict__ h,
                                                   const _Float16* __restrict__ wh,
                                                   const float* __restrict__ bc,
                                                   _Float16* __restrict__ z, int n) {
    __shared__ half8 wls[128 * 16];   // row r chunk c at r*16 + (c^(r&15))
    int tid = threadIdx.x;
    int lane = tid & 63, w = tid >> 6;
    int quad = lane >> 4, m16 = lane & 15;
    int nb = blockIdx.x * 64;
    #pragma unroll
    for (int i = 0; i < 8; ++i) {
        int g = tid + 256 * i;   // 0..2047 chunk id = r*16 + c
        int r = g >> 4, c = g & 15;
        wls[r * 16 + (c ^ (r & 15))] = ((const half8*)wh)[g];
    }
    // preload A-frags: node row = nb + w*16 + m16, chunk = kk*4 + quad
    int arow = nb + w * 16 + m16;      // may run past n; stays inside d_ws
    const half8* hrow = (const half8*)(h + (size_t)arow * N_CH);
    half8 a[4];
    #pragma unroll
    for (int kk = 0; kk < 4; ++kk) a[kk] = hrow[kk * 4 + quad];
    __syncthreads();
    int outnode0 = nb + w * 16 + quad * 4;
    #pragma unroll
    for (int jt = 0; jt < 8; ++jt) {
        floatx4 acc = {0.f, 0.f, 0.f, 0.f};
        #pragma unroll
        for (int kk = 0; kk < 4; ++kk) {
            int r = jt * 16 + m16;
            half8 bfr = wls[r * 16 + ((kk * 4 + quad) ^ m16)];
            acc = __builtin_amdgcn_mfma_f32_16x16x32_f16(a[kk], bfr, acc, 0, 0, 0);
        }
        int j = jt * 16 + m16;
        float bias = bc[j];
        #pragma unroll
        for (int reg = 0; reg < 4; ++reg) {
            int node = outnode0 + reg;
            if (node < n) z[(size_t)node * N_CH + j] = (_Float16)(acc[reg] + bias);
        }
    }
}

// ---------------- decode: fp16 MFMA, 64 pairs x 64 hidden per block ----------------

__global__ __launch_bounds__(256) void k_decode_mfma(const _Float16* __restrict__ z,
        const int* __restrict__ ai, const int* __restrict__ bi,
        const _Float16* __restrict__ w1h, const float* __restrict__ b1,
        const float* __restrict__ w2, const float* __restrict__ b2,
        float* __restrict__ out, int m) {
    __shared__ half8 w1ls[64 * 16];
    __shared__ half8 sls[64 * 16];
    int tid = threadIdx.x;
    int lane = tid & 63, w = tid >> 6;
    int quad = lane >> 4, m16 = lane & 15;
    int pbase = blockIdx.x * 64;
    #pragma unroll
    for (int i = 0; i < 4; ++i) {
        int g = tid + 256 * i;   // 0..1023
        int r = g >> 4, c = g & 15;
        w1ls[r * 16 + (c ^ (r & 15))] = ((const half8*)w1h)[g];
    }
    // pair indices: lane holds pair (w*16 + (lane&15))
    int pidx = pbase + w * 16 + m16;
    if (pidx >= m) pidx = m - 1;
    int idxa = ai[pidx];
    int idxb = bi[pidx];
    // staging: lane&15 = chunk, lane>>4 = pair-in-group; preload all 8 rows
    int ia[4], ib[4];
    #pragma unroll
    for (int it = 0; it < 4; ++it) {
        int p = it * 4 + quad;
        ia[it] = __shfl(idxa, p, 64);
        ib[it] = __shfl(idxb, p, 64);
    }
    half8 za[4], zb[4];
    #pragma unroll
    for (int it = 0; it < 4; ++it) {
        za[it] = ((const half8*)(z + (size_t)ia[it] * N_CH))[m16];
        zb[it] = ((const half8*)(z + (size_t)ib[it] * N_CH))[m16];
    }
    #pragma unroll
    for (int it = 0; it < 4; ++it) {
        half8 s8 = za[it] * zb[it];        // v_pk_mul_f16
        int pp = w * 16 + it * 4 + quad;
        sls[pp * 16 + (m16 ^ (pp & 15))] = s8;
    }
    __syncthreads();
    // A-frags: row p = w*16 + m16 (p&15 == m16)
    half8 a[4];
    #pragma unroll
    for (int kk = 0; kk < 4; ++kk)
        a[kk] = sls[(w * 16 + m16) * 16 + ((kk * 4 + quad) ^ m16)];
    float rsum[4] = {0.f, 0.f, 0.f, 0.f};
    #pragma unroll
    for (int jt = 0; jt < 4; ++jt) {
        floatx4 acc = {0.f, 0.f, 0.f, 0.f};
        #pragma unroll
        for (int kk = 0; kk < 4; ++kk) {
            int r = jt * 16 + m16;
            half8 bfr = w1ls[r * 16 + ((kk * 4 + quad) ^ m16)];
            acc = __builtin_amdgcn_mfma_f32_16x16x32_f16(a[kk], bfr, acc, 0, 0, 0);
        }
        int j = jt * 16 + m16;
        float b1j = b1[j], w2j = w2[j];
        #pragma unroll
        for (int reg = 0; reg < 4; ++reg) {
            float v = fmaxf(acc[reg] + b1j, 0.f) * w2j;
            v += __shfl_xor(v, 1, 64);
            v += __shfl_xor(v, 2, 64);
            v += __shfl_xor(v, 4, 64);
            v += __shfl_xor(v, 8, 64);
            rsum[reg] += v;          // valid at m16==0 lanes
        }
    }
    if (m16 == 0) {
        float bb = b2[0];
        #pragma unroll
        for (int reg = 0; reg < 4; ++reg) {
            int gp = pbase + w * 16 + quad * 4 + reg;
            if (gp < m) out[gp] = rsum[reg] + bb;
        }
    }
}

// ---------------- launch ----------------

extern "C" void kernel_launch(void* const* d_in, const int* in_sizes, int n_in,
                              void* d_out, int out_size, void* d_ws, size_t ws_size,
                              hipStream_t stream) {
    const float* x   = (const float*)d_in[0];
    const int*   ei  = (const int*)d_in[1];
    const int*   eli = (const int*)d_in[2];
    const float* W   = (const float*)d_in[3];
    const float* bc  = (const float*)d_in[4];
    const float* W1  = (const float*)d_in[5];
    const float* b1  = (const float*)d_in[6];
    const float* w2  = (const float*)d_in[7];
    const float* b2  = (const float*)d_in[8];
    float* out = (float*)d_out;

    const int N = in_sizes[0] / N_CH;   // 50000
    const int E = in_sizes[1] / 2;      // 600000
    const int M = in_sizes[2] / 2;      // 200000
    const int NH = N / 2;               // bucket boundary

    const int* src = ei;
    const int* dst = ei + E;
    const int* ai  = eli;
    const int* bi  = eli + M;

    // workspace layout: two (N+1)-row fp16 buffers (row N = zero row)
    _Float16* hb0 = (_Float16*)d_ws;                       // (N+1)*128
    _Float16* hb1 = hb0 + (size_t)(N + 1) * N_CH;          // (N+1)*128
    _Float16* wh  = hb1 + (size_t)(N + 1) * N_CH;          // 16384
    _Float16* w1h = wh + 16384;                            // 8192
    unsigned short* csr = (unsigned short*)(w1h + 8192);   // E + 8N ushort (padded CSR)
    int*   cnt  = (int*)(csr + (size_t)E + 8 * (size_t)N); // N
    int*   cntl = cnt + N;                                 // N
    int*   off  = cntl + N;                                // N
    int*   curl = off + N;                                 // N
    int*   curh = curl + N;                                // N
    float* dnv  = (float*)(curh + N);                      // N
    int*   bsum = (int*)(dnv + N);                         // 64

    // 1) prep; bucketed CSR build (padded, hierarchical scan); scale x
    int nb = (N + 1023) / 1024;
    k_prep<<<(N + 255) / 256, 256, 0, stream>>>(cnt, cntl, W, wh, W1, w1h, N);
    k_count<<<(E + 255) / 256, 256, 0, stream>>>(src, dst, cnt, cntl, E, NH);
    k_scan1<<<nb, 1024, 0, stream>>>(cnt, off, bsum, N);
    k_scan3<<<(N + 255) / 256, 256, 0, stream>>>(cnt, cntl, off, bsum, curl, curh,
                                                 dnv, csr, N, nb);
    k_fill<<<(E + 255) / 256, 256, 0, stream>>>(src, dst, curl, curh, csr, E, NH);
    int sc_work = N * (N_CH / 4) + 64;
    k_scale<<<(sc_work + 255) / 256, 256, 0, stream>>>(x, dnv, hb0, hb1, N);

    // 2) two hops (each: two half-row passes in one dispatch, 32 nodes/block)
    int nblk = (N + 31) / 32;
    k_hop8<<<2 * nblk, 256, 0, stream>>>(hb0, hb1, off, cnt, dnv, csr, N, 1, nblk);
    k_hop8<<<2 * nblk, 256, 0, stream>>>(hb1, hb0, off, cnt, dnv, csr, N, 0, nblk);

    // 3) z = h2 @ W^T + bc  (fp16 MFMA, into hb1)
    k_zlin_mfma<<<(N + 63) / 64, 256, 0, stream>>>(hb0, wh, bc, hb1, N);

    // 4) decode (fp16 MFMA, 64 pairs x 64 hidden per block)
    k_decode_mfma<<<(M + 63) / 64, 256, 0, stream>>>(hb1, ai, bi, w1h, b1, w2, b2, out, M);
}

// Round 15
// 223.955 us; speedup vs baseline: 1.0403x; 1.0403x over previous
//
#include <hip/hip_runtime.h>

#define N_CH 128   // IN_CH == OUT_CH == 128

typedef _Float16 half8  __attribute__((ext_vector_type(8)));
typedef _Float16 half4v __attribute__((ext_vector_type(4)));
typedef float    floatx4 __attribute__((ext_vector_type(4)));

// ---------------- prep: zero cnt + W/W1 fp16 conversions ----------------

__global__ void k_prep(int* __restrict__ cnt,
                       const float* __restrict__ W,  _Float16* __restrict__ wh,
                       const float* __restrict__ W1, _Float16* __restrict__ w1h,
                       int n) {
    int i = blockIdx.x * blockDim.x + threadIdx.x;
    if (i < n) cnt[i] = 0;
    int nw4  = N_CH * N_CH / 4;
    int nw14 = 64 * N_CH / 4;
    if (i < nw4) {
        float4 v = ((const float4*)W)[i];
        half4v o;
        o[0] = (_Float16)v.x; o[1] = (_Float16)v.y; o[2] = (_Float16)v.z; o[3] = (_Float16)v.w;
        ((half4v*)wh)[i] = o;
    } else if (i < nw4 + nw14) {
        int j = i - nw4;
        float4 v = ((const float4*)W1)[j];
        half4v o;
        o[0] = (_Float16)v.x; o[1] = (_Float16)v.y; o[2] = (_Float16)v.z; o[3] = (_Float16)v.w;
        ((half4v*)w1h)[j] = o;
    }
}

// ---------------- CSR build ----------------

__global__ void k_count(const int* __restrict__ dst, int* __restrict__ cnt, int E) {
    int e = blockIdx.x * blockDim.x + threadIdx.x;
    if (e < E) atomicAdd(&cnt[dst[e]], 1);
}

// scan pass 1: per-block (1024) local exclusive scan of PADDED counts + block total
__global__ __launch_bounds__(1024) void k_scan1(const int* __restrict__ cnt,
                                                int* __restrict__ offs,
                                                int* __restrict__ bsum, int n) {
    __shared__ int ssum[16];
    int tid = threadIdx.x;
    int lane = tid & 63, wid = tid >> 6;
    int i = blockIdx.x * 1024 + tid;
    int v = (i < n) ? ((cnt[i] + 7) & ~7) : 0;   // pad to multiple of 8
    int x = v;
    #pragma unroll
    for (int off = 1; off < 64; off <<= 1) {
        int y = __shfl_up(x, off, 64);
        if (lane >= off) x += y;
    }
    if (lane == 63) ssum[wid] = x;
    __syncthreads();
    if (wid == 0 && lane < 16) {
        int s = ssum[lane];
        #pragma unroll
        for (int off = 1; off < 16; off <<= 1) {
            int y = __shfl_up(s, off, 64);
            if (lane >= off) s += y;
        }
        ssum[lane] = s;
    }
    __syncthreads();
    int waveoff = (wid > 0) ? ssum[wid - 1] : 0;
    int incl = x + waveoff;
    if (i < n) offs[i] = incl - v;          // local exclusive (padded)
    if (tid == 1023) bsum[blockIdx.x] = incl;
}

// scan pass 2 (fused block-sum prefix) + finalize: add base, cur, dinv, CSR tail pads
__global__ __launch_bounds__(256) void k_scan3(const int* __restrict__ cnt,
                                               int* __restrict__ offs,
                                               const int* __restrict__ bsum,
                                               int* __restrict__ cur,
                                               float* __restrict__ dinv,
                                               unsigned short* __restrict__ csr,
                                               int n, int nb) {
    __shared__ int sbb[64];
    int tid = threadIdx.x;
    if (tid < 64) {
        int v = (tid < nb) ? bsum[tid] : 0;
        int x = v;
        #pragma unroll
        for (int off = 1; off < 64; off <<= 1) {
            int y = __shfl_up(x, off, 64);
            if (tid >= off) x += y;
        }
        sbb[tid] = x - v;   // exclusive base per 1024-chunk
    }
    __syncthreads();
    int i = blockIdx.x * blockDim.x + tid;
    if (i < n) {
        int o = offs[i] + sbb[i >> 10];
        offs[i] = o;
        cur[i]  = o;
        int c = cnt[i];
        dinv[i] = rsqrtf((float)(c + 1));   // deg includes self-loop
        int cp = (c + 7) & ~7;
        unsigned short zn = (unsigned short)n;
        for (int j = c; j < cp; ++j) csr[o + j] = zn;   // pad -> zero row
    }
}

// fill: ushort src index (N < 65536); weights folded into pre-scaled rows
__global__ void k_fill(const int* __restrict__ src, const int* __restrict__ dst,
                       int* __restrict__ cur, unsigned short* __restrict__ csr, int E) {
    int e = blockIdx.x * blockDim.x + threadIdx.x;
    if (e < E) {
        int p = atomicAdd(&cur[dst[e]], 1);
        csr[p] = (unsigned short)src[e];
    }
}

// ---------------- u0 = fp16(dinv * x); zero row n of both buffers ----------------

__global__ void k_scale(const float* __restrict__ x, const float* __restrict__ dinv,
                        _Float16* __restrict__ u0, _Float16* __restrict__ u1, int n) {
    int i = blockIdx.x * blockDim.x + threadIdx.x;
    int nx4 = n * (N_CH / 4);
    if (i < nx4) {
        float d = dinv[i >> 5];
        float4 v = ((const float4*)x)[i];
        half4v o;
        o[0] = (_Float16)(d * v.x); o[1] = (_Float16)(d * v.y);
        o[2] = (_Float16)(d * v.z); o[3] = (_Float16)(d * v.w);
        ((half4v*)u0)[i] = o;
    } else if (i < nx4 + 64) {   // zero row n of u0 (32 granules) and u1 (32)
        int j = i - nx4;
        half4v zz; zz[0] = (_Float16)0.f; zz[1] = (_Float16)0.f; zz[2] = (_Float16)0.f; zz[3] = (_Float16)0.f;
        _Float16* dst16 = (j < 32) ? u0 : u1;
        ((half4v*)(dst16 + (size_t)n * N_CH))[j & 31] = zz;
    }
}

// ---------------- one hop, half-row split ----------------
// out[i] = scale_i * ( u[i] + sum_s u[s] ).
// Two passes per dispatch (pass = blockIdx >= nblk); pass p covers bytes
// [p*128, p*128+128) of every row -> per-pass gather working set 6.4 MB
// (fits aggregate L2 better; each gather = one full 128B line).
// 8-lane group per node (8 nodes/wave, 32/block); lane&7 = 16B chunk of the
// half-row; group-uniform uint4 load = 8 neighbor indices; 8 rows in flight
// per group (64 lines/wave); no cross-lane reduce.

__global__ __launch_bounds__(256) void k_hop8(const _Float16* __restrict__ hin,
                                              _Float16* __restrict__ hout,
                                              const int* __restrict__ offs,
                                              const int* __restrict__ cnt,
                                              const float* __restrict__ dinv,
                                              const unsigned short* __restrict__ csr,
                                              int n, int squared, int nblk) {
    int pass = (blockIdx.x >= nblk) ? 1 : 0;
    int bid  = blockIdx.x - pass * nblk;
    int tid  = threadIdx.x;
    int node = bid * 32 + (tid >> 3);
    int c8   = tid & 7;
    if (node >= n) return;
    int cbase = pass * 8 + c8;
    float di = dinv[node];
    float sc = squared ? di * di : di;
    int s0 = offs[node];
    int cp = (cnt[node] + 7) & ~7;          // padded count
    const uint4* qlst = (const uint4*)(csr + s0);   // 16B-aligned (offsets mult of 8)
    half8 self = ((const half8*)(hin + (size_t)node * N_CH))[cbase];
    float acc[8];
    #pragma unroll
    for (int j = 0; j < 8; ++j) acc[j] = (float)self[j];
    int nq = cp >> 3;
    for (int q = 0; q < nq; ++q) {
        uint4 pk = qlst[q];                 // group-uniform 8-index load
        int idx[8];
        idx[0] = pk.x & 0xFFFF; idx[1] = pk.x >> 16;
        idx[2] = pk.y & 0xFFFF; idx[3] = pk.y >> 16;
        idx[4] = pk.z & 0xFFFF; idx[5] = pk.z >> 16;
        idx[6] = pk.w & 0xFFFF; idx[7] = pk.w >> 16;
        half8 u[8];
        #pragma unroll
        for (int i = 0; i < 8; ++i)
            u[i] = ((const half8*)(hin + (size_t)idx[i] * N_CH))[cbase];
        #pragma unroll
        for (int i = 0; i < 8; ++i)
            #pragma unroll
            for (int j = 0; j < 8; ++j) acc[j] += (float)u[i][j];
    }
    half8 o;
    #pragma unroll
    for (int j = 0; j < 8; ++j) o[j] = (_Float16)(sc * acc[j]);
    ((half8*)(hout + (size_t)node * N_CH))[cbase] = o;
}

// ---------------- z = h @ W^T + b : fp16 MFMA GEMM ----------------
// block = 4 waves, tile 64 nodes x 128 out-ch. W (128x128 fp16) in swizzled LDS.
// mfma_f32_16x16x32_f16: A[m=lane&15][k=quad*8+j], B[n=lane&15][k=quad*8+j],
// D: col=lane&15, row=quad*4+reg.

__global__ __launch_bounds__(256) void k_zlin_mfma(const _Float16* __restrict__ h,
                                                   const _Float16* __restrict__ wh,
                                                   const float* __restrict__ bc,
                                                   _Float16* __restrict__ z, int n) {
    __shared__ half8 wls[128 * 16];   // row r chunk c at r*16 + (c^(r&15))
    int tid = threadIdx.x;
    int lane = tid & 63, w = tid >> 6;
    int quad = lane >> 4, m16 = lane & 15;
    int nb = blockIdx.x * 64;
    #pragma unroll
    for (int i = 0; i < 8; ++i) {
        int g = tid + 256 * i;   // 0..2047 chunk id = r*16 + c
        int r = g >> 4, c = g & 15;
        wls[r * 16 + (c ^ (r & 15))] = ((const half8*)wh)[g];
    }
    // preload A-frags: node row = nb + w*16 + m16, chunk = kk*4 + quad
    int arow = nb + w * 16 + m16;      // may run past n; stays inside d_ws
    const half8* hrow = (const half8*)(h + (size_t)arow * N_CH);
    half8 a[4];
    #pragma unroll
    for (int kk = 0; kk < 4; ++kk) a[kk] = hrow[kk * 4 + quad];
    __syncthreads();
    int outnode0 = nb + w * 16 + quad * 4;
    #pragma unroll
    for (int jt = 0; jt < 8; ++jt) {
        floatx4 acc = {0.f, 0.f, 0.f, 0.f};
        #pragma unroll
        for (int kk = 0; kk < 4; ++kk) {
            int r = jt * 16 + m16;
            half8 bfr = wls[r * 16 + ((kk * 4 + quad) ^ m16)];
            acc = __builtin_amdgcn_mfma_f32_16x16x32_f16(a[kk], bfr, acc, 0, 0, 0);
        }
        int j = jt * 16 + m16;
        float bias = bc[j];
        #pragma unroll
        for (int reg = 0; reg < 4; ++reg) {
            int node = outnode0 + reg;
            if (node < n) z[(size_t)node * N_CH + j] = (_Float16)(acc[reg] + bias);
        }
    }
}

// ---------------- decode: fp16 MFMA, 64 pairs x 64 hidden per block ----------------
// staging: all 8 z-row gathers preloaded before LDS stores; W1 LDS-resident;
// epilogue: +b1, relu, *w2, shuffle-reduce, +b2.

__global__ __launch_bounds__(256) void k_decode_mfma(const _Float16* __restrict__ z,
        const int* __restrict__ ai, const int* __restrict__ bi,
        const _Float16* __restrict__ w1h, const float* __restrict__ b1,
        const float* __restrict__ w2, const float* __restrict__ b2,
        float* __restrict__ out, int m) {
    __shared__ half8 w1ls[64 * 16];
    __shared__ half8 sls[64 * 16];
    int tid = threadIdx.x;
    int lane = tid & 63, w = tid >> 6;
    int quad = lane >> 4, m16 = lane & 15;
    int pbase = blockIdx.x * 64;
    #pragma unroll
    for (int i = 0; i < 4; ++i) {
        int g = tid + 256 * i;   // 0..1023
        int r = g >> 4, c = g & 15;
        w1ls[r * 16 + (c ^ (r & 15))] = ((const half8*)w1h)[g];
    }
    // pair indices: lane holds pair (w*16 + (lane&15))
    int pidx = pbase + w * 16 + m16;
    if (pidx >= m) pidx = m - 1;
    int idxa = ai[pidx];
    int idxb = bi[pidx];
    // staging: lane&15 = chunk, lane>>4 = pair-in-group; preload all 8 rows
    int ia[4], ib[4];
    #pragma unroll
    for (int it = 0; it < 4; ++it) {
        int p = it * 4 + quad;
        ia[it] = __shfl(idxa, p, 64);
        ib[it] = __shfl(idxb, p, 64);
    }
    half8 za[4], zb[4];
    #pragma unroll
    for (int it = 0; it < 4; ++it) {
        za[it] = ((const half8*)(z + (size_t)ia[it] * N_CH))[m16];
        zb[it] = ((const half8*)(z + (size_t)ib[it] * N_CH))[m16];
    }
    #pragma unroll
    for (int it = 0; it < 4; ++it) {
        half8 s8 = za[it] * zb[it];        // v_pk_mul_f16
        int pp = w * 16 + it * 4 + quad;
        sls[pp * 16 + (m16 ^ (pp & 15))] = s8;
    }
    __syncthreads();
    // A-frags: row p = w*16 + m16 (p&15 == m16)
    half8 a[4];
    #pragma unroll
    for (int kk = 0; kk < 4; ++kk)
        a[kk] = sls[(w * 16 + m16) * 16 + ((kk * 4 + quad) ^ m16)];
    float rsum[4] = {0.f, 0.f, 0.f, 0.f};
    #pragma unroll
    for (int jt = 0; jt < 4; ++jt) {
        floatx4 acc = {0.f, 0.f, 0.f, 0.f};
        #pragma unroll
        for (int kk = 0; kk < 4; ++kk) {
            int r = jt * 16 + m16;
            half8 bfr = w1ls[r * 16 + ((kk * 4 + quad) ^ m16)];
            acc = __builtin_amdgcn_mfma_f32_16x16x32_f16(a[kk], bfr, acc, 0, 0, 0);
        }
        int j = jt * 16 + m16;
        float b1j = b1[j], w2j = w2[j];
        #pragma unroll
        for (int reg = 0; reg < 4; ++reg) {
            float v = fmaxf(acc[reg] + b1j, 0.f) * w2j;
            v += __shfl_xor(v, 1, 64);
            v += __shfl_xor(v, 2, 64);
            v += __shfl_xor(v, 4, 64);
            v += __shfl_xor(v, 8, 64);
            rsum[reg] += v;          // valid at m16==0 lanes
        }
    }
    if (m16 == 0) {
        float bb = b2[0];
        #pragma unroll
        for (int reg = 0; reg < 4; ++reg) {
            int gp = pbase + w * 16 + quad * 4 + reg;
            if (gp < m) out[gp] = rsum[reg] + bb;
        }
    }
}

// ---------------- launch ----------------

extern "C" void kernel_launch(void* const* d_in, const int* in_sizes, int n_in,
                              void* d_out, int out_size, void* d_ws, size_t ws_size,
                              hipStream_t stream) {
    const float* x   = (const float*)d_in[0];
    const int*   ei  = (const int*)d_in[1];
    const int*   eli = (const int*)d_in[2];
    const float* W   = (const float*)d_in[3];
    const float* bc  = (const float*)d_in[4];
    const float* W1  = (const float*)d_in[5];
    const float* b1  = (const float*)d_in[6];
    const float* w2  = (const float*)d_in[7];
    const float* b2  = (const float*)d_in[8];
    float* out = (float*)d_out;

    const int N = in_sizes[0] / N_CH;   // 50000
    const int E = in_sizes[1] / 2;      // 600000
    const int M = in_sizes[2] / 2;      // 200000

    const int* src = ei;
    const int* dst = ei + E;
    const int* ai  = eli;
    const int* bi  = eli + M;

    // workspace layout: two (N+1)-row fp16 buffers (row N = zero row)
    _Float16* hb0 = (_Float16*)d_ws;                       // (N+1)*128
    _Float16* hb1 = hb0 + (size_t)(N + 1) * N_CH;          // (N+1)*128
    _Float16* wh  = hb1 + (size_t)(N + 1) * N_CH;          // 16384
    _Float16* w1h = wh + 16384;                            // 8192
    unsigned short* csr = (unsigned short*)(w1h + 8192);   // E + 8N ushort (padded CSR)
    int*   cnt  = (int*)(csr + (size_t)E + 8 * (size_t)N); // N
    int*   off  = cnt + N;                                 // N
    int*   cur  = off + N;                                 // N
    float* dnv  = (float*)(cur + N);                       // N
    int*   bsum = (int*)(dnv + N);                         // 64

    // 1) prep; CSR build (padded, hierarchical scan w/ fused pass2); scale x
    int nb = (N + 1023) / 1024;
    k_prep<<<(N + 255) / 256, 256, 0, stream>>>(cnt, W, wh, W1, w1h, N);
    k_count<<<(E + 255) / 256, 256, 0, stream>>>(dst, cnt, E);
    k_scan1<<<nb, 1024, 0, stream>>>(cnt, off, bsum, N);
    k_scan3<<<(N + 255) / 256, 256, 0, stream>>>(cnt, off, bsum, cur, dnv, csr, N, nb);
    k_fill<<<(E + 255) / 256, 256, 0, stream>>>(src, dst, cur, csr, E);
    int sc_work = N * (N_CH / 4) + 64;
    k_scale<<<(sc_work + 255) / 256, 256, 0, stream>>>(x, dnv, hb0, hb1, N);

    // 2) two hops (each: two half-row passes in one dispatch, 32 nodes/block)
    int nblk = (N + 31) / 32;
    k_hop8<<<2 * nblk, 256, 0, stream>>>(hb0, hb1, off, cnt, dnv, csr, N, 1, nblk);
    k_hop8<<<2 * nblk, 256, 0, stream>>>(hb1, hb0, off, cnt, dnv, csr, N, 0, nblk);

    // 3) z = h2 @ W^T + bc  (fp16 MFMA, into hb1)
    k_zlin_mfma<<<(N + 63) / 64, 256, 0, stream>>>(hb0, wh, bc, hb1, N);

    // 4) decode (fp16 MFMA, 64 pairs x 64 hidden per block)
    k_decode_mfma<<<(M + 63) / 64, 256, 0, stream>>>(hb1, ai, bi, w1h, b1, w2, b2, out, M);
}